// Round 6
// baseline (382.246 us; speedup 1.0000x reference)
//
#include <hip/hip_runtime.h>
#include <hip/hip_bf16.h>

typedef unsigned short u16;
typedef unsigned int u32;
typedef float floatx4 __attribute__((ext_vector_type(4)));
typedef __bf16 bf16x8 __attribute__((ext_vector_type(8)));
typedef __bf16 bf16x4 __attribute__((ext_vector_type(4)));
typedef u16 ushort4v __attribute__((ext_vector_type(4)));
typedef u16 ushort8v __attribute__((ext_vector_type(8)));
typedef short short4v __attribute__((ext_vector_type(4)));

#define DEVI static __device__ __forceinline__

DEVI u16 f2bf(float f) {
    u32 u = __builtin_bit_cast(u32, f);
    u += 0x7fffu + ((u >> 16) & 1u);   // round-to-nearest-even
    return (u16)(u >> 16);
}

DEVI float fexp2(float x) { return __builtin_amdgcn_exp2f(x); }  // v_exp_f32

// 16x16x16 bf16 MFMA (K=16): A 2 regs, B 2 regs, D 4 regs.
DEVI floatx4 mfma16(bf16x4 a, bf16x4 b, floatx4 c) {
#if __has_builtin(__builtin_amdgcn_mfma_f32_16x16x16_bf16)
    return __builtin_amdgcn_mfma_f32_16x16x16_bf16(a, b, c, 0, 0, 0);
#elif __has_builtin(__builtin_amdgcn_mfma_f32_16x16x16bf16_1k)
    return __builtin_amdgcn_mfma_f32_16x16x16bf16_1k(
        __builtin_bit_cast(short4v, a), __builtin_bit_cast(short4v, b), c, 0, 0, 0);
#else
    floatx4 d = c;
    asm("v_mfma_f32_16x16x16_bf16 %0, %1, %2, %0" : "+v"(d) : "v"(a), "v"(b));
    return d;
#endif
}

// async global->LDS, 16B per lane. dst must be wave-uniform base; HW adds lane*16.
DEVI void async_cp16(const u16* g, u16* l) {
    __builtin_amdgcn_global_load_lds((const __attribute__((address_space(1))) u32*)g,
                                     (__attribute__((address_space(3))) u32*)l, 16, 0, 0);
}

// ---------------------------------------------------------------------------
// GEMM: C[M,N] = A[M,K](bf16) @ W[N,K](bf16)^T, double-buffered one-barrier
// K-loop, async global_load_lds staging with XOR swizzle.
// SPLITK: grid.x doubled; half = bx/NX works on K-range [half*K, half*K+K)
// of rows with stride lda, writing fp32 partials to o0/o1.
// ---------------------------------------------------------------------------
template<int BM, int BN, int RW, int CW, bool QKV3, bool SPLITK,
         bool BIAS, bool RELU, bool RESID, bool OBF16>
__global__ __launch_bounds__(256) void gemm_nt(
    const u16* __restrict__ A,
    const u16* __restrict__ W0, const u16* __restrict__ W1, const u16* __restrict__ W2,
    const float* __restrict__ bias, const float* __restrict__ resid,
    void* __restrict__ o0, void* __restrict__ o1, void* __restrict__ o2,
    int K, int lda, int Nper, int NX)
{
    static_assert(RW * CW == 4, "4 waves");
    constexpr int WM = BM / RW, WN = BN / CW;
    constexpr int MI = WM / 16, NI = WN / 16;
    __shared__ __align__(16) u16 As[2][BM * 32];
    __shared__ __align__(16) u16 Bs[2][BN * 32];
    const int tid = threadIdx.x;
    const int w = tid >> 6, lane = tid & 63;
    const int q = lane >> 4, ml = lane & 15;
    const int wr = w / CW, wc = w % CW;
    const int m0 = blockIdx.y * BM;
    int bx = blockIdx.x;
    size_t kbase = 0;
    int half = 0;
    if (SPLITK) { half = bx / NX; bx -= half * NX; kbase = (size_t)half * K; }
    int n0 = bx * BN;
    const u16* W = W0;
    void* outp = o0;
    if (QKV3) {
        int sel = n0 / Nper;
        n0 -= sel * Nper;
        W = (sel == 0) ? W0 : (sel == 1 ? W1 : W2);
        outp = (sel == 0) ? o0 : (sel == 1 ? o1 : o2);
    }
    if (SPLITK) outp = half ? o1 : o0;

    auto stage = [&](int buf, int kt) {
#pragma unroll
        for (int p = 0; p < BM / 64; ++p) {
            int g = p * 256 + tid;
            int r = g >> 2, s = g & 3;
            int c = s ^ ((r >> 1) & 3);
            async_cp16(A + (size_t)(m0 + r) * lda + kbase + kt + c * 8,
                       &As[buf][(p * 256 + w * 64) * 8]);
        }
#pragma unroll
        for (int p = 0; p < BN / 64; ++p) {
            int g = p * 256 + tid;
            int r = g >> 2, s = g & 3;
            int c = s ^ ((r >> 1) & 3);
            async_cp16(W + (size_t)(n0 + r) * lda + kbase + kt + c * 8,
                       &Bs[buf][(p * 256 + w * 64) * 8]);
        }
    };

    const floatx4 fzero = {0.f, 0.f, 0.f, 0.f};
    floatx4 acc[MI][NI];
#pragma unroll
    for (int i = 0; i < MI; ++i)
#pragma unroll
        for (int j = 0; j < NI; ++j) acc[i][j] = fzero;

    stage(0, 0);
    for (int it = 0, kt = 0; kt < K; ++it, kt += 32) {
        __syncthreads();
        if (kt + 32 < K) stage((it + 1) & 1, kt + 32);
        const u16* Asb = As[it & 1];
        const u16* Bsb = Bs[it & 1];
        bf16x8 af[MI], bfr[NI];
#pragma unroll
        for (int i = 0; i < MI; ++i) {
            int rm = wr * WM + i * 16 + ml;
            int s = q ^ ((rm >> 1) & 3);
            af[i] = *(const bf16x8*)&Asb[(rm * 4 + s) * 8];
        }
#pragma unroll
        for (int j = 0; j < NI; ++j) {
            int rn = wc * WN + j * 16 + ml;
            int s = q ^ ((rn >> 1) & 3);
            bfr[j] = *(const bf16x8*)&Bsb[(rn * 4 + s) * 8];
        }
#pragma unroll
        for (int i = 0; i < MI; ++i)
#pragma unroll
            for (int j = 0; j < NI; ++j)
                acc[i][j] = __builtin_amdgcn_mfma_f32_16x16x32_bf16(af[i], bfr[j], acc[i][j], 0, 0, 0);
    }

    // epilogue: C/D layout col=lane&15, row=(lane>>4)*4+reg
#pragma unroll
    for (int j = 0; j < NI; ++j) {
        int gn = n0 + wc * WN + j * 16 + ml;
        float bj = 0.f;
        if (BIAS) bj = bias[gn];
#pragma unroll
        for (int i = 0; i < MI; ++i) {
            int gm0 = m0 + wr * WM + i * 16 + q * 4;
#pragma unroll
            for (int r = 0; r < 4; ++r) {
                size_t idx = (size_t)(gm0 + r) * Nper + gn;
                float v = acc[i][j][r] + bj;
                if (RELU) v = fmaxf(v, 0.f);
                if (RESID) v += resid[idx];
                if (OBF16) ((u16*)outp)[idx] = f2bf(v);
                else       ((float*)outp)[idx] = v;
            }
        }
    }
}

// ---------------------------------------------------------------------------
// Flash attention v5: transposed-S formulation, zero P round-trip.
// Block = 64 queries of one (b,h); 4 waves x 16 queries.
//   S^T = K @ Q^T   (16x16x32 MFMA, A=K rows from LDS, B=Q frags in regs)
//   -> lane holds P^T for query=ml, keys cf*16+q*4+r : exactly the B-operand
//      layout (k=quad*4+j) of a 16x16x16 MFMA.
//   O^T = V^T @ P^T (16x16x16 MFMA, A=Vt rows via ds_read_b64)
// No P LDS writes/reads, no lgkmcnt drain, scalar per-lane lsum (reduced once
// at epilogue via 2 shfls). LDS 32 KB -> 4 blocks/CU at the 1024-block grid.
// Q,K: [b*2048+s][h*64+d] bf16.  Vt: [b*1024+h*64+d][s] bf16.
// ---------------------------------------------------------------------------
__global__ __launch_bounds__(256, 4) void flash5(
    const u16* __restrict__ Q, const u16* __restrict__ Kg,
    const u16* __restrict__ Vt, const float* __restrict__ biasv,
    u16* __restrict__ O)
{
    __shared__ __align__(16) u16 Ks[2][64 * 64];
    __shared__ __align__(16) u16 Vs[2][64 * 64];
    const int tid = threadIdx.x;
    const int w = tid >> 6, lane = tid & 63;
    const int q = lane >> 4, ml = lane & 15;
    const int b = blockIdx.y >> 4, h = blockIdx.y & 15;
    const size_t rowQ = (size_t)(b * 2048 + blockIdx.x * 64);
    const float KSC = 0.125f * 1.4426950408889634f;   // /sqrt(64) * log2(e)
    const floatx4 fzero = {0.f, 0.f, 0.f, 0.f};

    // Q B-fragments (query = ml, d = q*8+j (+32)), direct from global
    bf16x8 qa[2];
#pragma unroll
    for (int c = 0; c < 2; ++c)
        qa[c] = *(const bf16x8*)&Q[(rowQ + w * 16 + ml) * 1024 + h * 64 + q * 8 + c * 32];

    auto stage = [&](int buf, int s0) {
#pragma unroll
        for (int p = 0; p < 2; ++p) {
            int L = p * 256 + tid;
            int row = L >> 3, sl = L & 7;
            int ch = sl ^ (row & 7);          // LDS[row][sl] holds global chunk ch
            async_cp16(Kg + (size_t)(b * 2048 + s0 + row) * 1024 + h * 64 + ch * 8,
                       &Ks[buf][(p * 256 + w * 64) * 8]);
            async_cp16(Vt + (size_t)(b * 1024 + h * 64 + row) * 2048 + s0 + ch * 8,
                       &Vs[buf][(p * 256 + w * 64) * 8]);
        }
    };

    floatx4 oacc[4];   // O^T: lane = (query ml, d = dt*16 + q*4 + r)
    float lsum = 0.f;  // per-lane partial: query ml, keys {cf*16+q*4+r}
#pragma unroll
    for (int d = 0; d < 4; ++d) oacc[d] = fzero;

    stage(0, 0);
    for (int it = 0; it < 32; ++it) {
        __syncthreads();
        if (it + 1 < 32) stage((it + 1) & 1, (it + 1) * 64);
        const u16* Kb = Ks[it & 1];
        const u16* Vb = Vs[it & 1];
        const int s0 = it * 64;

        // S^T per cf: A = K rows (key = cf*16+ml), B = qa. Then p = exp2.
        bf16x4 pfrag[4];
#pragma unroll
        for (int cf = 0; cf < 4; ++cf) {
            int krow = cf * 16 + ml;
            bf16x8 k0 = *(const bf16x8*)&Kb[krow * 64 + ((q + 0) ^ (krow & 7)) * 8];
            bf16x8 k1 = *(const bf16x8*)&Kb[krow * 64 + ((q + 4) ^ (krow & 7)) * 8];
            floatx4 t = fzero;
            t = __builtin_amdgcn_mfma_f32_16x16x32_bf16(k0, qa[0], t, 0, 0, 0);
            t = __builtin_amdgcn_mfma_f32_16x16x32_bf16(k1, qa[1], t, 0, 0, 0);
            const float4 bb = *(const float4*)&biasv[b * 2048 + s0 + cf * 16 + q * 4];
            float p0 = fexp2(fmaf(t[0], KSC, bb.x));
            float p1 = fexp2(fmaf(t[1], KSC, bb.y));
            float p2 = fexp2(fmaf(t[2], KSC, bb.z));
            float p3 = fexp2(fmaf(t[3], KSC, bb.w));
            lsum += (p0 + p1) + (p2 + p3);
            // pack to bf16x4 (round-half-up; bias cancels in P/sum(P))
            u32 lo01 = (__builtin_bit_cast(u32, p0) + 0x8000u) >> 16;
            u32 hi01 = (__builtin_bit_cast(u32, p1) + 0x8000u) & 0xffff0000u;
            u32 lo23 = (__builtin_bit_cast(u32, p2) + 0x8000u) >> 16;
            u32 hi23 = (__builtin_bit_cast(u32, p3) + 0x8000u) & 0xffff0000u;
            u32 pk[2] = {lo01 | hi01, lo23 | hi23};
            pfrag[cf] = __builtin_bit_cast(bf16x4, *(ulong1*)pk);
        }
        // O^T += V^T @ P^T : A = Vt rows (d = dt*16+ml), k = keys cf*16+q*4+j
#pragma unroll
        for (int dt = 0; dt < 4; ++dt) {
            int vrow = dt * 16 + ml;
#pragma unroll
            for (int cf = 0; cf < 4; ++cf) {
                int sl = (cf * 2 + (q >> 1)) ^ (vrow & 7);
                bf16x4 vf = *(const bf16x4*)&Vb[vrow * 64 + sl * 8 + (q & 1) * 4];
                oacc[dt] = mfma16(vf, pfrag[cf], oacc[dt]);
            }
        }
    }
    // lsum total for query ml: reduce across the 4 quads
    lsum += __shfl_xor(lsum, 16, 64);
    lsum += __shfl_xor(lsum, 32, 64);
    const float rcp = 1.f / lsum;
    const size_t row = rowQ + w * 16 + ml;
#pragma unroll
    for (int dt = 0; dt < 4; ++dt)
#pragma unroll
        for (int rp = 0; rp < 4; rp += 2) {
            u32 pk = (u32)f2bf(oacc[dt][rp] * rcp)
                   | ((u32)f2bf(oacc[dt][rp + 1] * rcp) << 16);
            *(u32*)&O[row * 1024 + h * 64 + dt * 16 + q * 4 + rp] = pk;
        }
}

// V [b*2048+s][h*64+d] -> Vt [b*1024+h*64+d][s], 64x64 tiles via LDS
__global__ __launch_bounds__(256) void vtrans(const u16* __restrict__ Vb, u16* __restrict__ Vt)
{
    __shared__ __align__(16) u16 T[64 * 72];
    const int tid = threadIdx.x;
    const int ct = blockIdx.x, rt = blockIdx.y;
    const int b = rt >> 5;
    const int s0 = (rt & 31) * 64;
    const int c0 = ct * 64;
#pragma unroll
    for (int p = 0; p < 2; ++p) {
        int slot = p * 256 + tid;
        int lr = slot >> 3, pc = slot & 7;
        bf16x8 v = *(const bf16x8*)&Vb[(size_t)(b * 2048 + s0 + lr) * 1024 + c0 + pc * 8];
        *(bf16x8*)&T[lr * 72 + pc * 8] = v;
    }
    __syncthreads();
#pragma unroll
    for (int p = 0; p < 2; ++p) {
        int slot = p * 256 + tid;
        int dc = slot >> 3, sc0 = (slot & 7) * 8;
        ushort8v o;
#pragma unroll
        for (int j = 0; j < 8; ++j) o[j] = T[(sc0 + j) * 72 + dc];
        *(ushort8v*)&Vt[(size_t)(b * 1024 + c0 + dc) * 2048 + s0 + sc0] = o;
    }
}

// LayerNorm (torch semantics: ddof=1 variance, eps added to std), fp32 -> bf16
__global__ __launch_bounds__(256) void ln_bf16(const float* __restrict__ x,
    const float* __restrict__ ga, const float* __restrict__ gb, u16* __restrict__ y)
{
    const int row = blockIdx.x, tid = threadIdx.x;
    const float4 v = ((const float4*)(x + (size_t)row * 1024))[tid];
    float s = v.x + v.y + v.z + v.w;
    float ss = v.x * v.x + v.y * v.y + v.z * v.z + v.w * v.w;
#pragma unroll
    for (int d = 1; d < 64; d <<= 1) { s += __shfl_xor(s, d, 64); ss += __shfl_xor(ss, d, 64); }
    __shared__ float ps[4], pss[4];
    const int w = tid >> 6, lane = tid & 63;
    if (lane == 0) { ps[w] = s; pss[w] = ss; }
    __syncthreads();
    s = ps[0] + ps[1] + ps[2] + ps[3];
    ss = pss[0] + pss[1] + pss[2] + pss[3];
    float mean = s * (1.f / 1024.f);
    float var = fmaxf((ss - s * mean) * (1.f / 1023.f), 0.f);
    float sc = ga[0] / (sqrtf(var) + 1e-6f);
    float bb = gb[0];
    ushort4v o;
    o[0] = f2bf((v.x - mean) * sc + bb);
    o[1] = f2bf((v.y - mean) * sc + bb);
    o[2] = f2bf((v.z - mean) * sc + bb);
    o[3] = f2bf((v.w - mean) * sc + bb);
    ((ushort4v*)(y + (size_t)row * 1024))[tid] = o;
}

// all 6 weight casts in one launch (12M elements = 3M float4)
__global__ __launch_bounds__(256) void cast_all(
    const float* __restrict__ wq, const float* __restrict__ wk,
    const float* __restrict__ wv, const float* __restrict__ wo,
    const float* __restrict__ w1, const float* __restrict__ w2,
    u16* __restrict__ wqb, u16* __restrict__ wkb, u16* __restrict__ wvb,
    u16* __restrict__ wob, u16* __restrict__ w1b, u16* __restrict__ w2b)
{
    size_t i = (size_t)blockIdx.x * 256 + threadIdx.x;   // float4 index
    const float* s; u16* d; size_t off;
    if (i < 262144)       { s = wq; d = wqb; off = i; }
    else if (i < 524288)  { s = wk; d = wkb; off = i - 262144; }
    else if (i < 786432)  { s = wv; d = wvb; off = i - 524288; }
    else if (i < 1048576) { s = wo; d = wob; off = i - 786432; }
    else if (i < 2097152) { s = w1; d = w1b; off = i - 1048576; }
    else                  { s = w2; d = w2b; off = i - 2097152; }
    float4 v = ((const float4*)s)[off];
    ushort4v o = {f2bf(v.x), f2bf(v.y), f2bf(v.z), f2bf(v.w)};
    ((ushort4v*)d)[off] = o;
}

// mask -> additive log2-domain bias
__global__ __launch_bounds__(256) void mask_bias(const int* __restrict__ m, float* __restrict__ bias)
{
    int i = blockIdx.x * 256 + threadIdx.x;
    if (i < 4096) bias[i] = m[i] ? 0.f : -1.442695e9f;
}

// FF2 finish: out = P0 + P1 + b2[col] + resid
__global__ __launch_bounds__(256) void ff2_fin(const float* __restrict__ p0, const float* __restrict__ p1,
    const float* __restrict__ b2, const float* __restrict__ resid, float* __restrict__ out)
{
    const size_t i = (size_t)blockIdx.x * 256 + threadIdx.x;   // float4 index
    float4 a = ((const float4*)p0)[i];
    float4 b = ((const float4*)p1)[i];
    float4 r = ((const float4*)resid)[i];
    float4 bb = ((const float4*)b2)[i & 255];
    float4 o = {a.x + b.x + r.x + bb.x, a.y + b.y + r.y + bb.y,
                a.z + b.z + r.z + bb.z, a.w + b.w + r.w + bb.w};
    ((float4*)out)[i] = o;
}

extern "C" void kernel_launch(void* const* d_in, const int* in_sizes, int n_in,
                              void* d_out, int out_size, void* d_ws, size_t ws_size,
                              hipStream_t stream)
{
    const float* src = (const float*)d_in[0];
    const int* msk   = (const int*)d_in[1];
    const float* wq  = (const float*)d_in[2];
    const float* wk  = (const float*)d_in[3];
    const float* wv  = (const float*)d_in[4];
    const float* wo  = (const float*)d_in[5];
    const float* w1  = (const float*)d_in[6];
    const float* b1  = (const float*)d_in[7];
    const float* w2  = (const float*)d_in[8];
    const float* b2  = (const float*)d_in[9];
    const float* a1  = (const float*)d_in[10];
    const float* be1 = (const float*)d_in[11];
    const float* a2  = (const float*)d_in[12];
    const float* be2 = (const float*)d_in[13];
    float* out = (float*)d_out;

    char* ws = (char*)d_ws;
    const size_t MB = (size_t)1 << 20;
    u16* wqb  = (u16*)(ws + 0 * MB);
    u16* wkb  = (u16*)(ws + 2 * MB);
    u16* wvb  = (u16*)(ws + 4 * MB);
    u16* wob  = (u16*)(ws + 6 * MB);
    u16* w1b  = (u16*)(ws + 8 * MB);    // 8..16
    u16* w2b  = (u16*)(ws + 16 * MB);   // 16..24
    u16* xln1 = (u16*)(ws + 24 * MB);   // 24..32; dead after QKV; aliased by attn
    u16* attn = xln1;
    u16* Qb   = (u16*)(ws + 32 * MB);   // 32..40; dead after flash; aliased by xln2
    u16* xln2 = Qb;
    u16* Kb   = (u16*)(ws + 40 * MB);   // 40..48
    u16* Vb   = (u16*)(ws + 48 * MB);   // 48..56
    u16* Vt   = (u16*)(ws + 56 * MB);   // 56..64
    float* biasv = (float*)(ws + 64 * MB);  // 16 KB in 64..72 spare
    u16* h1   = (u16*)(ws + 40 * MB);   // 32 MB: 40..72 (Kb/Vb/Vt dead by then)
    float* src2 = (float*)(ws + 72 * MB); // 16 MB: 72..88
    float* P0 = (float*)(ws + 0 * MB);   // 0..16  (weight casts dead by FF2)
    float* P1 = (float*)(ws + 24 * MB);  // 24..40 (attn/xln2 dead by FF2)

    cast_all<<<12288, 256, 0, stream>>>(wq, wk, wv, wo, w1, w2,
                                        wqb, wkb, wvb, wob, w1b, w2b);
    mask_bias<<<16, 256, 0, stream>>>(msk, biasv);

    ln_bf16<<<4096, 256, 0, stream>>>(src, a1, be1, xln1);

    // fused QKV: N_total=3072, per-block weight/output select
    gemm_nt<128, 128, 2, 2, true, false, false, false, false, true><<<dim3(24, 32), 256, 0, stream>>>(
        xln1, wqb, wkb, wvb, nullptr, nullptr, Qb, Kb, Vb, 1024, 1024, 1024, 0);

    vtrans<<<dim3(16, 64), 256, 0, stream>>>(Vb, Vt);

    flash5<<<dim3(32, 32), 256, 0, stream>>>(Qb, Kb, Vt, biasv, attn);

    // O-projection + residual (fp32)
    gemm_nt<128, 64, 4, 1, false, false, false, false, true, false><<<dim3(16, 32), 256, 0, stream>>>(
        attn, wob, nullptr, nullptr, nullptr, src, src2, nullptr, nullptr, 1024, 1024, 1024, 0);

    ln_bf16<<<4096, 256, 0, stream>>>(src2, a2, be2, xln2);

    // FF1: bias + ReLU -> bf16
    gemm_nt<128, 128, 2, 2, false, false, true, true, false, true><<<dim3(32, 32), 256, 0, stream>>>(
        xln2, w1b, nullptr, nullptr, b1, nullptr, h1, nullptr, nullptr, 1024, 1024, 4096, 0);

    // FF2: split-K=2 into fp32 partials
    gemm_nt<128, 128, 2, 2, false, true, false, false, false, false><<<dim3(16, 32), 256, 0, stream>>>(
        h1, w2b, nullptr, nullptr, nullptr, nullptr, P0, P1, nullptr, 2048, 4096, 1024, 8);

    // out = P0 + P1 + b2 + src2
    ff2_fin<<<4096, 256, 0, stream>>>(P0, P1, b2, src2, out);
}

// Round 7
// 378.603 us; speedup vs baseline: 1.0096x; 1.0096x over previous
//
#include <hip/hip_runtime.h>
#include <hip/hip_bf16.h>

typedef unsigned short u16;
typedef unsigned int u32;
typedef float floatx4 __attribute__((ext_vector_type(4)));
typedef __bf16 bf16x8 __attribute__((ext_vector_type(8)));
typedef __bf16 bf16x4 __attribute__((ext_vector_type(4)));
typedef u16 ushort4v __attribute__((ext_vector_type(4)));
typedef u16 ushort8v __attribute__((ext_vector_type(8)));
typedef short short4v __attribute__((ext_vector_type(4)));

#define DEVI static __device__ __forceinline__

DEVI u16 f2bf(float f) {
    u32 u = __builtin_bit_cast(u32, f);
    u += 0x7fffu + ((u >> 16) & 1u);   // round-to-nearest-even
    return (u16)(u >> 16);
}

DEVI float fexp2(float x) { return __builtin_amdgcn_exp2f(x); }  // v_exp_f32

// 16x16x16 bf16 MFMA (K=16): A 2 regs, B 2 regs, D 4 regs.
DEVI floatx4 mfma16(bf16x4 a, bf16x4 b, floatx4 c) {
#if __has_builtin(__builtin_amdgcn_mfma_f32_16x16x16_bf16)
    return __builtin_amdgcn_mfma_f32_16x16x16_bf16(a, b, c, 0, 0, 0);
#elif __has_builtin(__builtin_amdgcn_mfma_f32_16x16x16bf16_1k)
    return __builtin_amdgcn_mfma_f32_16x16x16bf16_1k(
        __builtin_bit_cast(short4v, a), __builtin_bit_cast(short4v, b), c, 0, 0, 0);
#else
    floatx4 d = c;
    asm("v_mfma_f32_16x16x16_bf16 %0, %1, %2, %0" : "+v"(d) : "v"(a), "v"(b));
    return d;
#endif
}

// async global->LDS, 16B per lane. dst must be wave-uniform base; HW adds lane*16.
DEVI void async_cp16(const u16* g, u16* l) {
    __builtin_amdgcn_global_load_lds((const __attribute__((address_space(1))) u32*)g,
                                     (__attribute__((address_space(3))) u32*)l, 16, 0, 0);
}

// ---------------------------------------------------------------------------
// GEMM: C[M,N] = A[M,K](bf16) @ W[N,K](bf16)^T, double-buffered one-barrier
// K-loop, async global_load_lds staging with XOR swizzle.
// SPLITK: grid.x doubled; half = bx/NX works on K-range [half*K, half*K+K)
// of rows with stride lda, writing fp32 partials to o0/o1.
// ---------------------------------------------------------------------------
template<int BM, int BN, int RW, int CW, bool QKV3, bool SPLITK,
         bool BIAS, bool RELU, bool RESID, bool OBF16>
__global__ __launch_bounds__(256) void gemm_nt(
    const u16* __restrict__ A,
    const u16* __restrict__ W0, const u16* __restrict__ W1, const u16* __restrict__ W2,
    const float* __restrict__ bias, const float* __restrict__ resid,
    void* __restrict__ o0, void* __restrict__ o1, void* __restrict__ o2,
    int K, int lda, int Nper, int NX)
{
    static_assert(RW * CW == 4, "4 waves");
    constexpr int WM = BM / RW, WN = BN / CW;
    constexpr int MI = WM / 16, NI = WN / 16;
    __shared__ __align__(16) u16 As[2][BM * 32];
    __shared__ __align__(16) u16 Bs[2][BN * 32];
    const int tid = threadIdx.x;
    const int w = tid >> 6, lane = tid & 63;
    const int q = lane >> 4, ml = lane & 15;
    const int wr = w / CW, wc = w % CW;
    const int m0 = blockIdx.y * BM;
    int bx = blockIdx.x;
    size_t kbase = 0;
    int half = 0;
    if (SPLITK) { half = bx / NX; bx -= half * NX; kbase = (size_t)half * K; }
    int n0 = bx * BN;
    const u16* W = W0;
    void* outp = o0;
    if (QKV3) {
        int sel = n0 / Nper;
        n0 -= sel * Nper;
        W = (sel == 0) ? W0 : (sel == 1 ? W1 : W2);
        outp = (sel == 0) ? o0 : (sel == 1 ? o1 : o2);
    }
    if (SPLITK) outp = half ? o1 : o0;

    auto stage = [&](int buf, int kt) {
#pragma unroll
        for (int p = 0; p < BM / 64; ++p) {
            int g = p * 256 + tid;
            int r = g >> 2, s = g & 3;
            int c = s ^ ((r >> 1) & 3);
            async_cp16(A + (size_t)(m0 + r) * lda + kbase + kt + c * 8,
                       &As[buf][(p * 256 + w * 64) * 8]);
        }
#pragma unroll
        for (int p = 0; p < BN / 64; ++p) {
            int g = p * 256 + tid;
            int r = g >> 2, s = g & 3;
            int c = s ^ ((r >> 1) & 3);
            async_cp16(W + (size_t)(n0 + r) * lda + kbase + kt + c * 8,
                       &Bs[buf][(p * 256 + w * 64) * 8]);
        }
    };

    const floatx4 fzero = {0.f, 0.f, 0.f, 0.f};
    floatx4 acc[MI][NI];
#pragma unroll
    for (int i = 0; i < MI; ++i)
#pragma unroll
        for (int j = 0; j < NI; ++j) acc[i][j] = fzero;

    stage(0, 0);
    for (int it = 0, kt = 0; kt < K; ++it, kt += 32) {
        __syncthreads();
        if (kt + 32 < K) stage((it + 1) & 1, kt + 32);
        const u16* Asb = As[it & 1];
        const u16* Bsb = Bs[it & 1];
        bf16x8 af[MI], bfr[NI];
#pragma unroll
        for (int i = 0; i < MI; ++i) {
            int rm = wr * WM + i * 16 + ml;
            int s = q ^ ((rm >> 1) & 3);
            af[i] = *(const bf16x8*)&Asb[(rm * 4 + s) * 8];
        }
#pragma unroll
        for (int j = 0; j < NI; ++j) {
            int rn = wc * WN + j * 16 + ml;
            int s = q ^ ((rn >> 1) & 3);
            bfr[j] = *(const bf16x8*)&Bsb[(rn * 4 + s) * 8];
        }
#pragma unroll
        for (int i = 0; i < MI; ++i)
#pragma unroll
            for (int j = 0; j < NI; ++j)
                acc[i][j] = __builtin_amdgcn_mfma_f32_16x16x32_bf16(af[i], bfr[j], acc[i][j], 0, 0, 0);
    }

    // epilogue: C/D layout col=lane&15, row=(lane>>4)*4+reg
#pragma unroll
    for (int j = 0; j < NI; ++j) {
        int gn = n0 + wc * WN + j * 16 + ml;
        float bj = 0.f;
        if (BIAS) bj = bias[gn];
#pragma unroll
        for (int i = 0; i < MI; ++i) {
            int gm0 = m0 + wr * WM + i * 16 + q * 4;
#pragma unroll
            for (int r = 0; r < 4; ++r) {
                size_t idx = (size_t)(gm0 + r) * Nper + gn;
                float v = acc[i][j][r] + bj;
                if (RELU) v = fmaxf(v, 0.f);
                if (RESID) v += resid[idx];
                if (OBF16) ((u16*)outp)[idx] = f2bf(v);
                else       ((float*)outp)[idx] = v;
            }
        }
    }
}

// ---------------------------------------------------------------------------
// Flash attention v6: transposed-S, zero P round-trip, conflict-free V reads.
// Block = 64 queries of one (b,h); 4 waves x 16 queries.
//   S^T = K @ Q^T (16x16x32 MFMA) -> lane P^T is directly the B-operand of a
//   16x16x16 MFMA; O^T = V^T @ P^T with V^T A-frags from LDS.
// V̂ global layout (built by vtrans): per 64-key block, 16B chunk c=p*4+q holds
// the cf=2p and cf=2p+1 A-fragments for quad q (keys 32p+q*4+j, 32p+16+q*4+j)
// -> V reads are 8 ds_read_b128/iter with the SAME (proven conflict-free)
// slot=c^(row&7) pattern as the K reads. Fixes flash5's 8.4M conflict cycles.
// Q,K: [b*2048+s][h*64+d] bf16.  V̂: [b*1024+h*64+d][2048 interleaved] bf16.
// ---------------------------------------------------------------------------
__global__ __launch_bounds__(256, 4) void flash6(
    const u16* __restrict__ Q, const u16* __restrict__ Kg,
    const u16* __restrict__ Vt, const float* __restrict__ biasv,
    u16* __restrict__ O)
{
    __shared__ __align__(16) u16 Ks[2][64 * 64];
    __shared__ __align__(16) u16 Vs[2][64 * 64];
    const int tid = threadIdx.x;
    const int w = tid >> 6, lane = tid & 63;
    const int q = lane >> 4, ml = lane & 15;
    const int b = blockIdx.y >> 4, h = blockIdx.y & 15;
    const size_t rowQ = (size_t)(b * 2048 + blockIdx.x * 64);
    const float KSC = 0.125f * 1.4426950408889634f;   // /sqrt(64) * log2(e)
    const floatx4 fzero = {0.f, 0.f, 0.f, 0.f};

    // Q B-fragments (query = ml, d = q*8+j (+32)), direct from global
    bf16x8 qa[2];
#pragma unroll
    for (int c = 0; c < 2; ++c)
        qa[c] = *(const bf16x8*)&Q[(rowQ + w * 16 + ml) * 1024 + h * 64 + q * 8 + c * 32];

    auto stage = [&](int buf, int s0) {
#pragma unroll
        for (int p = 0; p < 2; ++p) {
            int L = p * 256 + tid;
            int row = L >> 3, sl = L & 7;
            int ch = sl ^ (row & 7);          // LDS[row][sl] holds global chunk ch
            async_cp16(Kg + (size_t)(b * 2048 + s0 + row) * 1024 + h * 64 + ch * 8,
                       &Ks[buf][(p * 256 + w * 64) * 8]);
            async_cp16(Vt + (size_t)(b * 1024 + h * 64 + row) * 2048 + s0 + ch * 8,
                       &Vs[buf][(p * 256 + w * 64) * 8]);
        }
    };

    floatx4 oacc[4];   // O^T tile dt: lane holds d=dt*16+q*4+r, query=ml
    float lsum = 0.f;  // per-lane partial: query ml, keys {cf*16+q*4+r}
#pragma unroll
    for (int d = 0; d < 4; ++d) oacc[d] = fzero;

    stage(0, 0);
    for (int it = 0; it < 32; ++it) {
        __syncthreads();
        if (it + 1 < 32) stage((it + 1) & 1, (it + 1) * 64);
        const u16* Kb = Ks[it & 1];
        const u16* Vb = Vs[it & 1];
        const int s0 = it * 64;

        // S^T per cf: A = K rows (key = cf*16+ml), B = qa. Then p = exp2.
        bf16x4 pfrag[4];
#pragma unroll
        for (int cf = 0; cf < 4; ++cf) {
            int krow = cf * 16 + ml;
            bf16x8 k0 = *(const bf16x8*)&Kb[krow * 64 + ((q + 0) ^ (krow & 7)) * 8];
            bf16x8 k1 = *(const bf16x8*)&Kb[krow * 64 + ((q + 4) ^ (krow & 7)) * 8];
            floatx4 t = fzero;
            t = __builtin_amdgcn_mfma_f32_16x16x32_bf16(k0, qa[0], t, 0, 0, 0);
            t = __builtin_amdgcn_mfma_f32_16x16x32_bf16(k1, qa[1], t, 0, 0, 0);
            const float4 bb = *(const float4*)&biasv[b * 2048 + s0 + cf * 16 + q * 4];
            float p0 = fexp2(fmaf(t[0], KSC, bb.x));
            float p1 = fexp2(fmaf(t[1], KSC, bb.y));
            float p2 = fexp2(fmaf(t[2], KSC, bb.z));
            float p3 = fexp2(fmaf(t[3], KSC, bb.w));
            lsum += (p0 + p1) + (p2 + p3);
            // pack to bf16x4 (round-half-up; bias cancels in P/sum(P))
            u32 lo01 = (__builtin_bit_cast(u32, p0) + 0x8000u) >> 16;
            u32 hi01 = (__builtin_bit_cast(u32, p1) + 0x8000u) & 0xffff0000u;
            u32 lo23 = (__builtin_bit_cast(u32, p2) + 0x8000u) >> 16;
            u32 hi23 = (__builtin_bit_cast(u32, p3) + 0x8000u) & 0xffff0000u;
            u32 pk[2] = {lo01 | hi01, lo23 | hi23};
            pfrag[cf] = __builtin_bit_cast(bf16x4, *(ulong1*)pk);
        }
        // O^T += V^T @ P^T : A-frag pairs via one b128 per (dt, cf-pair)
#pragma unroll
        for (int dt = 0; dt < 4; ++dt) {
            int vrow = dt * 16 + ml;
#pragma unroll
            for (int p = 0; p < 2; ++p) {
                int slot = (p * 4 + q) ^ (vrow & 7);
                bf16x8 vv = *(const bf16x8*)&Vb[vrow * 64 + slot * 8];
                bf16x4 v0 = {vv[0], vv[1], vv[2], vv[3]};
                bf16x4 v1 = {vv[4], vv[5], vv[6], vv[7]};
                oacc[dt] = mfma16(v0, pfrag[2 * p + 0], oacc[dt]);
                oacc[dt] = mfma16(v1, pfrag[2 * p + 1], oacc[dt]);
            }
        }
    }
    // lsum total for query ml: reduce across the 4 quads
    lsum += __shfl_xor(lsum, 16, 64);
    lsum += __shfl_xor(lsum, 32, 64);
    const float rcp = 1.f / lsum;
    const size_t row = rowQ + w * 16 + ml;
#pragma unroll
    for (int dt = 0; dt < 4; ++dt)
#pragma unroll
        for (int rp = 0; rp < 4; rp += 2) {
            u32 pk = (u32)f2bf(oacc[dt][rp] * rcp)
                   | ((u32)f2bf(oacc[dt][rp + 1] * rcp) << 16);
            *(u32*)&O[row * 1024 + h * 64 + dt * 16 + q * 4 + rp] = pk;
        }
}

// V [b*2048+s][h*64+d] -> V̂ [b*1024+h*64+d][2048], where each 64-key block is
// interleaved: position c*8+e (16B chunk c=p*4+q) holds key 32p+(e>>2)*16+q*4+(e&3).
__global__ __launch_bounds__(256) void vtrans(const u16* __restrict__ Vb, u16* __restrict__ Vt)
{
    __shared__ __align__(16) u16 T[64 * 72];
    const int tid = threadIdx.x;
    const int ct = blockIdx.x, rt = blockIdx.y;
    const int b = rt >> 5;
    const int s0 = (rt & 31) * 64;
    const int c0 = ct * 64;
#pragma unroll
    for (int p = 0; p < 2; ++p) {
        int slot = p * 256 + tid;
        int lr = slot >> 3, pc = slot & 7;
        bf16x8 v = *(const bf16x8*)&Vb[(size_t)(b * 2048 + s0 + lr) * 1024 + c0 + pc * 8];
        *(bf16x8*)&T[lr * 72 + pc * 8] = v;
    }
    __syncthreads();
#pragma unroll
    for (int pp = 0; pp < 2; ++pp) {
        int slot = pp * 256 + tid;
        int dc = slot >> 3, c = slot & 7;
        ushort8v o;
#pragma unroll
        for (int e = 0; e < 8; ++e) {
            int k = (c >> 2) * 32 + (e >> 2) * 16 + (c & 3) * 4 + (e & 3);
            o[e] = T[k * 72 + dc];
        }
        *(ushort8v*)&Vt[(size_t)(b * 1024 + c0 + dc) * 2048 + s0 + c * 8] = o;
    }
}

// LayerNorm (torch semantics: ddof=1 variance, eps added to std), fp32 -> bf16
__global__ __launch_bounds__(256) void ln_bf16(const float* __restrict__ x,
    const float* __restrict__ ga, const float* __restrict__ gb, u16* __restrict__ y)
{
    const int row = blockIdx.x, tid = threadIdx.x;
    const float4 v = ((const float4*)(x + (size_t)row * 1024))[tid];
    float s = v.x + v.y + v.z + v.w;
    float ss = v.x * v.x + v.y * v.y + v.z * v.z + v.w * v.w;
#pragma unroll
    for (int d = 1; d < 64; d <<= 1) { s += __shfl_xor(s, d, 64); ss += __shfl_xor(ss, d, 64); }
    __shared__ float ps[4], pss[4];
    const int w = tid >> 6, lane = tid & 63;
    if (lane == 0) { ps[w] = s; pss[w] = ss; }
    __syncthreads();
    s = ps[0] + ps[1] + ps[2] + ps[3];
    ss = pss[0] + pss[1] + pss[2] + pss[3];
    float mean = s * (1.f / 1024.f);
    float var = fmaxf((ss - s * mean) * (1.f / 1023.f), 0.f);
    float sc = ga[0] / (sqrtf(var) + 1e-6f);
    float bb = gb[0];
    ushort4v o;
    o[0] = f2bf((v.x - mean) * sc + bb);
    o[1] = f2bf((v.y - mean) * sc + bb);
    o[2] = f2bf((v.z - mean) * sc + bb);
    o[3] = f2bf((v.w - mean) * sc + bb);
    ((ushort4v*)(y + (size_t)row * 1024))[tid] = o;
}

// all 6 weight casts in one launch (12M elements = 3M float4)
__global__ __launch_bounds__(256) void cast_all(
    const float* __restrict__ wq, const float* __restrict__ wk,
    const float* __restrict__ wv, const float* __restrict__ wo,
    const float* __restrict__ w1, const float* __restrict__ w2,
    u16* __restrict__ wqb, u16* __restrict__ wkb, u16* __restrict__ wvb,
    u16* __restrict__ wob, u16* __restrict__ w1b, u16* __restrict__ w2b)
{
    size_t i = (size_t)blockIdx.x * 256 + threadIdx.x;   // float4 index
    const float* s; u16* d; size_t off;
    if (i < 262144)       { s = wq; d = wqb; off = i; }
    else if (i < 524288)  { s = wk; d = wkb; off = i - 262144; }
    else if (i < 786432)  { s = wv; d = wvb; off = i - 524288; }
    else if (i < 1048576) { s = wo; d = wob; off = i - 786432; }
    else if (i < 2097152) { s = w1; d = w1b; off = i - 1048576; }
    else                  { s = w2; d = w2b; off = i - 2097152; }
    float4 v = ((const float4*)s)[off];
    ushort4v o = {f2bf(v.x), f2bf(v.y), f2bf(v.z), f2bf(v.w)};
    ((ushort4v*)d)[off] = o;
}

// mask -> additive log2-domain bias
__global__ __launch_bounds__(256) void mask_bias(const int* __restrict__ m, float* __restrict__ bias)
{
    int i = blockIdx.x * 256 + threadIdx.x;
    if (i < 4096) bias[i] = m[i] ? 0.f : -1.442695e9f;
}

// FF2 finish: out = P0 + P1 + b2[col] + resid
__global__ __launch_bounds__(256) void ff2_fin(const float* __restrict__ p0, const float* __restrict__ p1,
    const float* __restrict__ b2, const float* __restrict__ resid, float* __restrict__ out)
{
    const size_t i = (size_t)blockIdx.x * 256 + threadIdx.x;   // float4 index
    float4 a = ((const float4*)p0)[i];
    float4 b = ((const float4*)p1)[i];
    float4 r = ((const float4*)resid)[i];
    float4 bb = ((const float4*)b2)[i & 255];
    float4 o = {a.x + b.x + r.x + bb.x, a.y + b.y + r.y + bb.y,
                a.z + b.z + r.z + bb.z, a.w + b.w + r.w + bb.w};
    ((float4*)out)[i] = o;
}

extern "C" void kernel_launch(void* const* d_in, const int* in_sizes, int n_in,
                              void* d_out, int out_size, void* d_ws, size_t ws_size,
                              hipStream_t stream)
{
    const float* src = (const float*)d_in[0];
    const int* msk   = (const int*)d_in[1];
    const float* wq  = (const float*)d_in[2];
    const float* wk  = (const float*)d_in[3];
    const float* wv  = (const float*)d_in[4];
    const float* wo  = (const float*)d_in[5];
    const float* w1  = (const float*)d_in[6];
    const float* b1  = (const float*)d_in[7];
    const float* w2  = (const float*)d_in[8];
    const float* b2  = (const float*)d_in[9];
    const float* a1  = (const float*)d_in[10];
    const float* be1 = (const float*)d_in[11];
    const float* a2  = (const float*)d_in[12];
    const float* be2 = (const float*)d_in[13];
    float* out = (float*)d_out;

    char* ws = (char*)d_ws;
    const size_t MB = (size_t)1 << 20;
    u16* wqb  = (u16*)(ws + 0 * MB);
    u16* wkb  = (u16*)(ws + 2 * MB);
    u16* wvb  = (u16*)(ws + 4 * MB);
    u16* wob  = (u16*)(ws + 6 * MB);
    u16* w1b  = (u16*)(ws + 8 * MB);    // 8..16
    u16* w2b  = (u16*)(ws + 16 * MB);   // 16..24
    u16* xln1 = (u16*)(ws + 24 * MB);   // 24..32; dead after QKV; aliased by attn
    u16* attn = xln1;
    u16* Qb   = (u16*)(ws + 32 * MB);   // 32..40; dead after flash; aliased by xln2
    u16* xln2 = Qb;
    u16* Kb   = (u16*)(ws + 40 * MB);   // 40..48
    u16* Vb   = (u16*)(ws + 48 * MB);   // 48..56
    u16* Vt   = (u16*)(ws + 56 * MB);   // 56..64
    float* biasv = (float*)(ws + 64 * MB);  // 16 KB in 64..72 spare
    u16* h1   = (u16*)(ws + 40 * MB);   // 32 MB: 40..72 (Kb/Vb/Vt dead by then)
    float* src2 = (float*)(ws + 72 * MB); // 16 MB: 72..88
    float* P0 = (float*)(ws + 0 * MB);   // 0..16  (weight casts dead by FF2)
    float* P1 = (float*)(ws + 24 * MB);  // 24..40 (attn/xln2 dead by FF2)

    cast_all<<<12288, 256, 0, stream>>>(wq, wk, wv, wo, w1, w2,
                                        wqb, wkb, wvb, wob, w1b, w2b);
    mask_bias<<<16, 256, 0, stream>>>(msk, biasv);

    ln_bf16<<<4096, 256, 0, stream>>>(src, a1, be1, xln1);

    // fused QKV: N_total=3072, per-block weight/output select
    gemm_nt<128, 128, 2, 2, true, false, false, false, false, true><<<dim3(24, 32), 256, 0, stream>>>(
        xln1, wqb, wkb, wvb, nullptr, nullptr, Qb, Kb, Vb, 1024, 1024, 1024, 0);

    vtrans<<<dim3(16, 64), 256, 0, stream>>>(Vb, Vt);

    flash6<<<dim3(32, 32), 256, 0, stream>>>(Qb, Kb, Vt, biasv, attn);

    // O-projection + residual (fp32)
    gemm_nt<128, 64, 4, 1, false, false, false, false, true, false><<<dim3(16, 32), 256, 0, stream>>>(
        attn, wob, nullptr, nullptr, nullptr, src, src2, nullptr, nullptr, 1024, 1024, 1024, 0);

    ln_bf16<<<4096, 256, 0, stream>>>(src2, a2, be2, xln2);

    // FF1: bias + ReLU -> bf16
    gemm_nt<128, 128, 2, 2, false, false, true, true, false, true><<<dim3(32, 32), 256, 0, stream>>>(
        xln2, w1b, nullptr, nullptr, b1, nullptr, h1, nullptr, nullptr, 1024, 1024, 4096, 0);

    // FF2: split-K=2 into fp32 partials
    gemm_nt<128, 128, 2, 2, false, true, false, false, false, false><<<dim3(16, 32), 256, 0, stream>>>(
        h1, w2b, nullptr, nullptr, nullptr, nullptr, P0, P1, nullptr, 2048, 4096, 1024, 8);

    // out = P0 + P1 + b2 + src2
    ff2_fin<<<4096, 256, 0, stream>>>(P0, P1, b2, src2, out);
}

// Round 8
// 365.200 us; speedup vs baseline: 1.0467x; 1.0367x over previous
//
#include <hip/hip_runtime.h>
#include <hip/hip_bf16.h>

typedef unsigned short u16;
typedef unsigned int u32;
typedef float floatx4 __attribute__((ext_vector_type(4)));
typedef __bf16 bf16x8 __attribute__((ext_vector_type(8)));
typedef u16 ushort4v __attribute__((ext_vector_type(4)));
typedef u16 ushort8v __attribute__((ext_vector_type(8)));

#define DEVI static __device__ __forceinline__

DEVI u16 f2bf(float f) {
    u32 u = __builtin_bit_cast(u32, f);
    u += 0x7fffu + ((u >> 16) & 1u);   // round-to-nearest-even
    return (u16)(u >> 16);
}

DEVI float fexp2(float x) { return __builtin_amdgcn_exp2f(x); }  // v_exp_f32

// async global->LDS, 16B per lane. dst must be wave-uniform base; HW adds lane*16.
DEVI void async_cp16(const u16* g, u16* l) {
    __builtin_amdgcn_global_load_lds((const __attribute__((address_space(1))) u32*)g,
                                     (__attribute__((address_space(3))) u32*)l, 16, 0, 0);
}

// ---------------------------------------------------------------------------
// GEMM: C[M,N] = A[M,K](bf16) @ W[N,K](bf16)^T, double-buffered one-barrier
// K-loop, async global_load_lds staging with XOR swizzle.
// SPLITK: grid.x doubled; half = bx/NX works on K-range [half*K, half*K+K)
// of rows with stride lda, writing fp32 partials to o0/o1.
// ---------------------------------------------------------------------------
template<int BM, int BN, int RW, int CW, bool QKV3, bool SPLITK,
         bool BIAS, bool RELU, bool RESID, bool OBF16>
__global__ __launch_bounds__(256) void gemm_nt(
    const u16* __restrict__ A,
    const u16* __restrict__ W0, const u16* __restrict__ W1, const u16* __restrict__ W2,
    const float* __restrict__ bias, const float* __restrict__ resid,
    void* __restrict__ o0, void* __restrict__ o1, void* __restrict__ o2,
    int K, int lda, int Nper, int NX)
{
    static_assert(RW * CW == 4, "4 waves");
    constexpr int WM = BM / RW, WN = BN / CW;
    constexpr int MI = WM / 16, NI = WN / 16;
    __shared__ __align__(16) u16 As[2][BM * 32];
    __shared__ __align__(16) u16 Bs[2][BN * 32];
    const int tid = threadIdx.x;
    const int w = tid >> 6, lane = tid & 63;
    const int q = lane >> 4, ml = lane & 15;
    const int wr = w / CW, wc = w % CW;
    const int m0 = blockIdx.y * BM;
    int bx = blockIdx.x;
    size_t kbase = 0;
    int half = 0;
    if (SPLITK) { half = bx / NX; bx -= half * NX; kbase = (size_t)half * K; }
    int n0 = bx * BN;
    const u16* W = W0;
    void* outp = o0;
    if (QKV3) {
        int sel = n0 / Nper;
        n0 -= sel * Nper;
        W = (sel == 0) ? W0 : (sel == 1 ? W1 : W2);
        outp = (sel == 0) ? o0 : (sel == 1 ? o1 : o2);
    }
    if (SPLITK) outp = half ? o1 : o0;

    auto stage = [&](int buf, int kt) {
#pragma unroll
        for (int p = 0; p < BM / 64; ++p) {
            int g = p * 256 + tid;
            int r = g >> 2, s = g & 3;
            int c = s ^ ((r >> 1) & 3);
            async_cp16(A + (size_t)(m0 + r) * lda + kbase + kt + c * 8,
                       &As[buf][(p * 256 + w * 64) * 8]);
        }
#pragma unroll
        for (int p = 0; p < BN / 64; ++p) {
            int g = p * 256 + tid;
            int r = g >> 2, s = g & 3;
            int c = s ^ ((r >> 1) & 3);
            async_cp16(W + (size_t)(n0 + r) * lda + kbase + kt + c * 8,
                       &Bs[buf][(p * 256 + w * 64) * 8]);
        }
    };

    const floatx4 fzero = {0.f, 0.f, 0.f, 0.f};
    floatx4 acc[MI][NI];
#pragma unroll
    for (int i = 0; i < MI; ++i)
#pragma unroll
        for (int j = 0; j < NI; ++j) acc[i][j] = fzero;

    stage(0, 0);
    for (int it = 0, kt = 0; kt < K; ++it, kt += 32) {
        __syncthreads();
        if (kt + 32 < K) stage((it + 1) & 1, kt + 32);
        const u16* Asb = As[it & 1];
        const u16* Bsb = Bs[it & 1];
        bf16x8 af[MI], bfr[NI];
#pragma unroll
        for (int i = 0; i < MI; ++i) {
            int rm = wr * WM + i * 16 + ml;
            int s = q ^ ((rm >> 1) & 3);
            af[i] = *(const bf16x8*)&Asb[(rm * 4 + s) * 8];
        }
#pragma unroll
        for (int j = 0; j < NI; ++j) {
            int rn = wc * WN + j * 16 + ml;
            int s = q ^ ((rn >> 1) & 3);
            bfr[j] = *(const bf16x8*)&Bsb[(rn * 4 + s) * 8];
        }
#pragma unroll
        for (int i = 0; i < MI; ++i)
#pragma unroll
            for (int j = 0; j < NI; ++j)
                acc[i][j] = __builtin_amdgcn_mfma_f32_16x16x32_bf16(af[i], bfr[j], acc[i][j], 0, 0, 0);
    }

    // epilogue: C/D layout col=lane&15, row=(lane>>4)*4+reg
#pragma unroll
    for (int j = 0; j < NI; ++j) {
        int gn = n0 + wc * WN + j * 16 + ml;
        float bj = 0.f;
        if (BIAS) bj = bias[gn];
#pragma unroll
        for (int i = 0; i < MI; ++i) {
            int gm0 = m0 + wr * WM + i * 16 + q * 4;
#pragma unroll
            for (int r = 0; r < 4; ++r) {
                size_t idx = (size_t)(gm0 + r) * Nper + gn;
                float v = acc[i][j][r] + bj;
                if (RELU) v = fmaxf(v, 0.f);
                if (RESID) v += resid[idx];
                if (OBF16) ((u16*)outp)[idx] = f2bf(v);
                else       ((float*)outp)[idx] = v;
            }
        }
    }
}

// ---------------------------------------------------------------------------
// Flash attention v7: transposed-S + key-relabeled S^T so PV runs in 16x16x32.
// Block = 128 threads (2 waves) x 32 queries each = 64 queries; grid 1024.
//   S^T even/odd MFMAs feed A rows with keys (m>>2)*8+(m&3) (+4 for odd), so
//   the C output lane (q,ml) holds keys q*8+r / q*8+4+r -> packing even+odd
//   gives the 16x16x32 B-operand (k=q*8+j) IN-LANE. Zero shuffles, zero P
//   LDS traffic, PV back at x32 rate (flash6's mfma16 halved PV throughput).
// 32 queries/wave amortizes K/V LDS reads over 2x FLOPs (DS-pipe is the
// shared bottleneck). Swizzle sw(row)=(row&3)|(((row>>3)&1)<<2) keeps all
// reads <=2-way (free). Q,K: [b*2048+s][h*64+d].  Vt: [b*1024+h*64+d][s].
// ---------------------------------------------------------------------------
__global__ __launch_bounds__(128, 2) void flash7(
    const u16* __restrict__ Q, const u16* __restrict__ Kg,
    const u16* __restrict__ Vt, const float* __restrict__ biasv,
    u16* __restrict__ O)
{
    __shared__ __align__(16) u16 Ks[2][64 * 64];
    __shared__ __align__(16) u16 Vs[2][64 * 64];
    const int tid = threadIdx.x;
    const int w = tid >> 6, lane = tid & 63;
    const int q = lane >> 4, ml = lane & 15;
    const int b = blockIdx.y >> 4, h = blockIdx.y & 15;
    const size_t rowQ = (size_t)(b * 2048 + blockIdx.x * 64);
    const float KSC = 0.125f * 1.4426950408889634f;   // /sqrt(64) * log2(e)
    const floatx4 fzero = {0.f, 0.f, 0.f, 0.f};

    // Q B-fragments: query = w*32 + qg*16 + ml, d = q*8+j + c*32
    bf16x8 qa[2][2];
#pragma unroll
    for (int qg = 0; qg < 2; ++qg)
#pragma unroll
        for (int c = 0; c < 2; ++c)
            qa[qg][c] = *(const bf16x8*)&Q[(rowQ + w * 32 + qg * 16 + ml) * 1024
                                           + h * 64 + q * 8 + c * 32];

    auto stage = [&](int buf, int s0) {
#pragma unroll
        for (int p = 0; p < 4; ++p) {
            int L = p * 128 + tid;
            int row = L >> 3, sl = L & 7;
            int ch = sl ^ ((row & 3) | (((row >> 3) & 1) << 2));
            async_cp16(Kg + (size_t)(b * 2048 + s0 + row) * 1024 + h * 64 + ch * 8,
                       &Ks[buf][(p * 128 + w * 64) * 8]);
            async_cp16(Vt + (size_t)(b * 1024 + h * 64 + row) * 2048 + s0 + ch * 8,
                       &Vs[buf][(p * 128 + w * 64) * 8]);
        }
    };

    floatx4 oacc[2][4];          // [qg][dt]: lane = (d=dt*16+q*4+r, query=ml)
    float lsum[2] = {0.f, 0.f};  // per-lane partials, keys {q*8..q*8+7} per 32-grp
#pragma unroll
    for (int qg = 0; qg < 2; ++qg)
#pragma unroll
        for (int d = 0; d < 4; ++d) oacc[qg][d] = fzero;

    // lane-constant swizzles
    const int swk = (ml & 3) | (((ml >> 2) & 1) << 2);   // for K rows (ml>>2)*8+(ml&3)
    const int swv = (ml & 3) | (((ml >> 3) & 1) << 2);   // for V rows dt*16+ml

    stage(0, 0);
    for (int it = 0; it < 32; ++it) {
        __syncthreads();
        if (it + 1 < 32) stage((it + 1) & 1, (it + 1) * 64);
        const u16* Kb = Ks[it & 1];
        const u16* Vb = Vs[it & 1];
        const int s0 = it * 64;

        bf16x8 pfrag[2][2];   // [g][qg]
#pragma unroll
        for (int g = 0; g < 2; ++g) {
            const int re = g * 32 + ((ml >> 2) << 3) + (ml & 3);  // even rows
            bf16x8 ke0 = *(const bf16x8*)&Kb[(re + 0) * 64 + ((0 + q) ^ swk) * 8];
            bf16x8 ke1 = *(const bf16x8*)&Kb[(re + 0) * 64 + ((4 + q) ^ swk) * 8];
            bf16x8 ko0 = *(const bf16x8*)&Kb[(re + 4) * 64 + ((0 + q) ^ swk) * 8];
            bf16x8 ko1 = *(const bf16x8*)&Kb[(re + 4) * 64 + ((4 + q) ^ swk) * 8];
            const float4 be = *(const float4*)&biasv[b * 2048 + s0 + g * 32 + q * 8];
            const float4 bo = *(const float4*)&biasv[b * 2048 + s0 + g * 32 + q * 8 + 4];
#pragma unroll
            for (int qg = 0; qg < 2; ++qg) {
                floatx4 te = fzero, to = fzero;
                te = __builtin_amdgcn_mfma_f32_16x16x32_bf16(ke0, qa[qg][0], te, 0, 0, 0);
                te = __builtin_amdgcn_mfma_f32_16x16x32_bf16(ke1, qa[qg][1], te, 0, 0, 0);
                to = __builtin_amdgcn_mfma_f32_16x16x32_bf16(ko0, qa[qg][0], to, 0, 0, 0);
                to = __builtin_amdgcn_mfma_f32_16x16x32_bf16(ko1, qa[qg][1], to, 0, 0, 0);
                float pe0 = fexp2(fmaf(te[0], KSC, be.x));
                float pe1 = fexp2(fmaf(te[1], KSC, be.y));
                float pe2 = fexp2(fmaf(te[2], KSC, be.z));
                float pe3 = fexp2(fmaf(te[3], KSC, be.w));
                float po0 = fexp2(fmaf(to[0], KSC, bo.x));
                float po1 = fexp2(fmaf(to[1], KSC, bo.y));
                float po2 = fexp2(fmaf(to[2], KSC, bo.z));
                float po3 = fexp2(fmaf(to[3], KSC, bo.w));
                lsum[qg] += ((pe0 + pe1) + (pe2 + pe3)) + ((po0 + po1) + (po2 + po3));
                // pack round-half-up (bias cancels in P/sum(P)); j=0..3 even, 4..7 odd
                u32 pk[4];
                pk[0] = ((__builtin_bit_cast(u32, pe0) + 0x8000u) >> 16)
                      | ((__builtin_bit_cast(u32, pe1) + 0x8000u) & 0xffff0000u);
                pk[1] = ((__builtin_bit_cast(u32, pe2) + 0x8000u) >> 16)
                      | ((__builtin_bit_cast(u32, pe3) + 0x8000u) & 0xffff0000u);
                pk[2] = ((__builtin_bit_cast(u32, po0) + 0x8000u) >> 16)
                      | ((__builtin_bit_cast(u32, po1) + 0x8000u) & 0xffff0000u);
                pk[3] = ((__builtin_bit_cast(u32, po2) + 0x8000u) >> 16)
                      | ((__builtin_bit_cast(u32, po3) + 0x8000u) & 0xffff0000u);
                pfrag[g][qg] = __builtin_bit_cast(bf16x8, *(uint4*)pk);
            }
        }
        // O^T += V^T @ P^T : A = V rows d=dt*16+ml, keys g*32+q*8+j (chunk g*4+q)
#pragma unroll
        for (int dt = 0; dt < 4; ++dt) {
            int vrow = dt * 16 + ml;
#pragma unroll
            for (int g = 0; g < 2; ++g) {
                bf16x8 vf = *(const bf16x8*)&Vb[vrow * 64 + ((g * 4 + q) ^ swv) * 8];
#pragma unroll
                for (int qg = 0; qg < 2; ++qg)
                    oacc[qg][dt] = __builtin_amdgcn_mfma_f32_16x16x32_bf16(
                        vf, pfrag[g][qg], oacc[qg][dt], 0, 0, 0);
            }
        }
    }
#pragma unroll
    for (int qg = 0; qg < 2; ++qg) {
        float ls = lsum[qg];
        ls += __shfl_xor(ls, 16, 64);
        ls += __shfl_xor(ls, 32, 64);
        const float rcp = 1.f / ls;
        const size_t row = rowQ + w * 32 + qg * 16 + ml;
#pragma unroll
        for (int dt = 0; dt < 4; ++dt)
#pragma unroll
            for (int rp = 0; rp < 4; rp += 2) {
                u32 pk = (u32)f2bf(oacc[qg][dt][rp] * rcp)
                       | ((u32)f2bf(oacc[qg][dt][rp + 1] * rcp) << 16);
                *(u32*)&O[row * 1024 + h * 64 + dt * 16 + q * 4 + rp] = pk;
            }
    }
}

// V [b*2048+s][h*64+d] -> Vt [b*1024+h*64+d][s], 64x64 tiles via LDS
__global__ __launch_bounds__(256) void vtrans(const u16* __restrict__ Vb, u16* __restrict__ Vt)
{
    __shared__ __align__(16) u16 T[64 * 72];
    const int tid = threadIdx.x;
    const int ct = blockIdx.x, rt = blockIdx.y;
    const int b = rt >> 5;
    const int s0 = (rt & 31) * 64;
    const int c0 = ct * 64;
#pragma unroll
    for (int p = 0; p < 2; ++p) {
        int slot = p * 256 + tid;
        int lr = slot >> 3, pc = slot & 7;
        bf16x8 v = *(const bf16x8*)&Vb[(size_t)(b * 2048 + s0 + lr) * 1024 + c0 + pc * 8];
        *(bf16x8*)&T[lr * 72 + pc * 8] = v;
    }
    __syncthreads();
#pragma unroll
    for (int p = 0; p < 2; ++p) {
        int slot = p * 256 + tid;
        int dc = slot >> 3, sc0 = (slot & 7) * 8;
        ushort8v o;
#pragma unroll
        for (int j = 0; j < 8; ++j) o[j] = T[(sc0 + j) * 72 + dc];
        *(ushort8v*)&Vt[(size_t)(b * 1024 + c0 + dc) * 2048 + s0 + sc0] = o;
    }
}

// LayerNorm (torch semantics: ddof=1 variance, eps added to std), fp32 -> bf16
__global__ __launch_bounds__(256) void ln_bf16(const float* __restrict__ x,
    const float* __restrict__ ga, const float* __restrict__ gb, u16* __restrict__ y)
{
    const int row = blockIdx.x, tid = threadIdx.x;
    const float4 v = ((const float4*)(x + (size_t)row * 1024))[tid];
    float s = v.x + v.y + v.z + v.w;
    float ss = v.x * v.x + v.y * v.y + v.z * v.z + v.w * v.w;
#pragma unroll
    for (int d = 1; d < 64; d <<= 1) { s += __shfl_xor(s, d, 64); ss += __shfl_xor(ss, d, 64); }
    __shared__ float ps[4], pss[4];
    const int w = tid >> 6, lane = tid & 63;
    if (lane == 0) { ps[w] = s; pss[w] = ss; }
    __syncthreads();
    s = ps[0] + ps[1] + ps[2] + ps[3];
    ss = pss[0] + pss[1] + pss[2] + pss[3];
    float mean = s * (1.f / 1024.f);
    float var = fmaxf((ss - s * mean) * (1.f / 1023.f), 0.f);
    float sc = ga[0] / (sqrtf(var) + 1e-6f);
    float bb = gb[0];
    ushort4v o;
    o[0] = f2bf((v.x - mean) * sc + bb);
    o[1] = f2bf((v.y - mean) * sc + bb);
    o[2] = f2bf((v.z - mean) * sc + bb);
    o[3] = f2bf((v.w - mean) * sc + bb);
    ((ushort4v*)(y + (size_t)row * 1024))[tid] = o;
}

// all 6 weight casts in one launch (12M elements = 3M float4)
__global__ __launch_bounds__(256) void cast_all(
    const float* __restrict__ wq, const float* __restrict__ wk,
    const float* __restrict__ wv, const float* __restrict__ wo,
    const float* __restrict__ w1, const float* __restrict__ w2,
    u16* __restrict__ wqb, u16* __restrict__ wkb, u16* __restrict__ wvb,
    u16* __restrict__ wob, u16* __restrict__ w1b, u16* __restrict__ w2b)
{
    size_t i = (size_t)blockIdx.x * 256 + threadIdx.x;   // float4 index
    const float* s; u16* d; size_t off;
    if (i < 262144)       { s = wq; d = wqb; off = i; }
    else if (i < 524288)  { s = wk; d = wkb; off = i - 262144; }
    else if (i < 786432)  { s = wv; d = wvb; off = i - 524288; }
    else if (i < 1048576) { s = wo; d = wob; off = i - 786432; }
    else if (i < 2097152) { s = w1; d = w1b; off = i - 1048576; }
    else                  { s = w2; d = w2b; off = i - 2097152; }
    float4 v = ((const float4*)s)[off];
    ushort4v o = {f2bf(v.x), f2bf(v.y), f2bf(v.z), f2bf(v.w)};
    ((ushort4v*)d)[off] = o;
}

// mask -> additive log2-domain bias
__global__ __launch_bounds__(256) void mask_bias(const int* __restrict__ m, float* __restrict__ bias)
{
    int i = blockIdx.x * 256 + threadIdx.x;
    if (i < 4096) bias[i] = m[i] ? 0.f : -1.442695e9f;
}

// FF2 finish: out = P0 + P1 + b2[col] + resid
__global__ __launch_bounds__(256) void ff2_fin(const float* __restrict__ p0, const float* __restrict__ p1,
    const float* __restrict__ b2, const float* __restrict__ resid, float* __restrict__ out)
{
    const size_t i = (size_t)blockIdx.x * 256 + threadIdx.x;   // float4 index
    float4 a = ((const float4*)p0)[i];
    float4 b = ((const float4*)p1)[i];
    float4 r = ((const float4*)resid)[i];
    float4 bb = ((const float4*)b2)[i & 255];
    float4 o = {a.x + b.x + r.x + bb.x, a.y + b.y + r.y + bb.y,
                a.z + b.z + r.z + bb.z, a.w + b.w + r.w + bb.w};
    ((float4*)out)[i] = o;
}

extern "C" void kernel_launch(void* const* d_in, const int* in_sizes, int n_in,
                              void* d_out, int out_size, void* d_ws, size_t ws_size,
                              hipStream_t stream)
{
    const float* src = (const float*)d_in[0];
    const int* msk   = (const int*)d_in[1];
    const float* wq  = (const float*)d_in[2];
    const float* wk  = (const float*)d_in[3];
    const float* wv  = (const float*)d_in[4];
    const float* wo  = (const float*)d_in[5];
    const float* w1  = (const float*)d_in[6];
    const float* b1  = (const float*)d_in[7];
    const float* w2  = (const float*)d_in[8];
    const float* b2  = (const float*)d_in[9];
    const float* a1  = (const float*)d_in[10];
    const float* be1 = (const float*)d_in[11];
    const float* a2  = (const float*)d_in[12];
    const float* be2 = (const float*)d_in[13];
    float* out = (float*)d_out;

    char* ws = (char*)d_ws;
    const size_t MB = (size_t)1 << 20;
    u16* wqb  = (u16*)(ws + 0 * MB);
    u16* wkb  = (u16*)(ws + 2 * MB);
    u16* wvb  = (u16*)(ws + 4 * MB);
    u16* wob  = (u16*)(ws + 6 * MB);
    u16* w1b  = (u16*)(ws + 8 * MB);    // 8..16
    u16* w2b  = (u16*)(ws + 16 * MB);   // 16..24
    u16* xln1 = (u16*)(ws + 24 * MB);   // 24..32; dead after QKV; aliased by attn
    u16* attn = xln1;
    u16* Qb   = (u16*)(ws + 32 * MB);   // 32..40; dead after flash; aliased by xln2
    u16* xln2 = Qb;
    u16* Kb   = (u16*)(ws + 40 * MB);   // 40..48
    u16* Vb   = (u16*)(ws + 48 * MB);   // 48..56
    u16* Vt   = (u16*)(ws + 56 * MB);   // 56..64
    float* biasv = (float*)(ws + 64 * MB);  // 16 KB in 64..72 spare
    u16* h1   = (u16*)(ws + 40 * MB);   // 32 MB: 40..72 (Kb/Vb/Vt dead by then)
    float* src2 = (float*)(ws + 72 * MB); // 16 MB: 72..88
    float* P0 = (float*)(ws + 0 * MB);   // 0..16  (weight casts dead by FF2)
    float* P1 = (float*)(ws + 24 * MB);  // 24..40 (attn/xln2 dead by FF2)

    cast_all<<<12288, 256, 0, stream>>>(wq, wk, wv, wo, w1, w2,
                                        wqb, wkb, wvb, wob, w1b, w2b);
    mask_bias<<<16, 256, 0, stream>>>(msk, biasv);

    ln_bf16<<<4096, 256, 0, stream>>>(src, a1, be1, xln1);

    // fused QKV: N_total=3072, per-block weight/output select
    gemm_nt<128, 128, 2, 2, true, false, false, false, false, true><<<dim3(24, 32), 256, 0, stream>>>(
        xln1, wqb, wkb, wvb, nullptr, nullptr, Qb, Kb, Vb, 1024, 1024, 1024, 0);

    vtrans<<<dim3(16, 64), 256, 0, stream>>>(Vb, Vt);

    flash7<<<dim3(32, 32), 128, 0, stream>>>(Qb, Kb, Vt, biasv, attn);

    // O-projection + residual (fp32)
    gemm_nt<128, 64, 4, 1, false, false, false, false, true, false><<<dim3(16, 32), 256, 0, stream>>>(
        attn, wob, nullptr, nullptr, nullptr, src, src2, nullptr, nullptr, 1024, 1024, 1024, 0);

    ln_bf16<<<4096, 256, 0, stream>>>(src2, a2, be2, xln2);

    // FF1: bias + ReLU -> bf16
    gemm_nt<128, 128, 2, 2, false, false, true, true, false, true><<<dim3(32, 32), 256, 0, stream>>>(
        xln2, w1b, nullptr, nullptr, b1, nullptr, h1, nullptr, nullptr, 1024, 1024, 4096, 0);

    // FF2: split-K=2 into fp32 partials
    gemm_nt<128, 128, 2, 2, false, true, false, false, false, false><<<dim3(16, 32), 256, 0, stream>>>(
        h1, w2b, nullptr, nullptr, nullptr, nullptr, P0, P1, nullptr, 2048, 4096, 1024, 8);

    // out = P0 + P1 + b2 + src2
    ff2_fin<<<4096, 256, 0, stream>>>(P0, P1, b2, src2, out);
}